// Round 2
// baseline (630.882 us; speedup 1.0000x reference)
//
#include <hip/hip_runtime.h>
#include <math.h>

#define H_ 256
#define W_ 256
#define HW_ 65536
#define BHW_ 131072   // B*H*W, B=2
#define NPC 8388608   // BHW_*64

__device__ __forceinline__ float geluf(float x) {
    const float k0 = 0.7978845608028654f; // sqrt(2/pi)
    return 0.5f * x * (1.f + tanhf(k0 * (x + 0.044715f * x * x * x)));
}
__device__ __forceinline__ float siluf(float x) {
    return x / (1.f + expf(-x));
}

// ---------- fused Poisson: div + 20 Jacobi iters, one launch ----------
// 32 blocks: 2 batches x 4x4 tiles. Interior 64x64, halo 20 (clipped at image edge).
// Garbage from non-image tile edges propagates 1 cell/iter <= 19 < 20 halo ->
// interior exact after 20 iters.
__global__ __launch_bounds__(512) void k_poisson(const float* __restrict__ x,
                                                 float* __restrict__ gray) {
    __shared__ float u[104 * 105];
    __shared__ float dv[104 * 105];
    int bid = blockIdx.x;
    int b = bid >> 4, t = bid & 15;
    int qy = t >> 2, qx = t & 3;
    int y0i = qy << 6, x0i = qx << 6;
    int ys = max(y0i - 20, 0), ye = min(y0i + 83, 255);
    int xs = max(x0i - 20, 0), xe = min(x0i + 83, 255);
    int Ht = ye - ys + 1, Wt = xe - xs + 1;
    int ty = threadIdx.x >> 5, tx = threadIdx.x & 31;
    const float* x5 = x + ((size_t)(b * 9 + 5) << 16);
    const float* x6 = x + ((size_t)(b * 9 + 6) << 16);

    for (int yy = ty; yy < Ht; yy += 16) {
        for (int xx = tx; xx < Wt; xx += 32) {
            int gy = ys + yy, gx = xs + xx;
            int i00 = (gy << 8) + gx;
            float v5 = x5[i00], v6 = x6[i00];
            // gx_field = -0.5(x5+x6); gy_field = 0.5(x5-x6); div = fwd-diff sum
            float d = -0.5f * (v5 + v6) + 0.5f * (v5 - v6);
            if (gx > 0) d += 0.5f * (x5[i00 - 1] + x6[i00 - 1]);
            if (gy > 0) d -= 0.5f * (x5[i00 - 256] - x6[i00 - 256]);
            dv[yy * 105 + xx] = d;
            u[yy * 105 + xx] = 0.f;
        }
    }
    __syncthreads();

    float nv[7][4];
    for (int it = 0; it < 20; ++it) {
        #pragma unroll
        for (int i = 0; i < 7; ++i) {
            int yy = ty + i * 16;
            #pragma unroll
            for (int j = 0; j < 4; ++j) {
                int xx = tx + j * 32;
                if (yy < Ht && xx < Wt) {
                    int ym = yy > 0 ? yy - 1 : 0, yp = yy < Ht - 1 ? yy + 1 : Ht - 1;
                    int xm = xx > 0 ? xx - 1 : 0, xp = xx < Wt - 1 ? xx + 1 : Wt - 1;
                    nv[i][j] = (u[ym * 105 + xx] + u[yp * 105 + xx] +
                                u[yy * 105 + xm] + u[yy * 105 + xp] - dv[yy * 105 + xx]) * 0.25f;
                }
            }
        }
        __syncthreads();
        #pragma unroll
        for (int i = 0; i < 7; ++i) {
            int yy = ty + i * 16;
            #pragma unroll
            for (int j = 0; j < 4; ++j) {
                int xx = tx + j * 32;
                if (yy < Ht && xx < Wt) u[yy * 105 + xx] = nv[i][j];
            }
        }
        __syncthreads();
    }

    for (int iy = ty; iy < 64; iy += 16)
        for (int ix = tx; ix < 32 * 2; ix += 32) {
            int gy = y0i + iy, gx = x0i + ix;
            gray[((size_t)b << 16) + (gy << 8) + gx] = u[(gy - ys) * 105 + (gx - xs)];
        }
}

// ---------- recon convnet (unchanged) ----------
__global__ void k_conv1(const float* __restrict__ x, const float* __restrict__ wgt,
                        const float* __restrict__ bias, float* __restrict__ out) {
    __shared__ float ws[32 * 7 * 9];
    __shared__ float bs[32];
    for (int i = threadIdx.x; i < 32 * 7 * 9; i += blockDim.x) ws[i] = wgt[i];
    if (threadIdx.x < 32) bs[threadIdx.x] = bias[threadIdx.x];
    __syncthreads();
    int pix = blockIdx.x * blockDim.x + threadIdx.x;
    if (pix >= BHW_) return;
    int b = pix >> 16, hw = pix & 65535;
    int h = hw >> 8, w = hw & 255;
    float acc[32];
    #pragma unroll
    for (int o = 0; o < 32; ++o) acc[o] = bs[o];
    for (int kh = 0; kh < 3; ++kh) {
        int y = h + kh - 1;
        if ((unsigned)y >= 256u) continue;
        for (int kw = 0; kw < 3; ++kw) {
            int xx = w + kw - 1;
            if ((unsigned)xx >= 256u) continue;
            for (int ci = 0; ci < 7; ++ci) {
                float v = x[((size_t)(b * 9 + ci) << 16) + (y << 8) + xx];
                int wb = ci * 9 + kh * 3 + kw;
                #pragma unroll
                for (int o = 0; o < 32; ++o) acc[o] += v * ws[o * 63 + wb];
            }
        }
    }
    for (int o = 0; o < 32; ++o)
        out[((size_t)(b * 32 + o) << 16) + hw] = siluf(acc[o]);
}

__global__ void k_conv2(const float* __restrict__ in, const float* __restrict__ wgt,
                        const float* __restrict__ bias, float* __restrict__ out) {
    __shared__ float ws[32 * 32 * 9];
    __shared__ float bs[32];
    for (int i = threadIdx.x; i < 32 * 32 * 9; i += blockDim.x) ws[i] = wgt[i];
    if (threadIdx.x < 32) bs[threadIdx.x] = bias[threadIdx.x];
    __syncthreads();
    int pix = blockIdx.x * blockDim.x + threadIdx.x;
    if (pix >= BHW_) return;
    int b = pix >> 16, hw = pix & 65535;
    int h = hw >> 8, w = hw & 255;
    float acc[32];
    #pragma unroll
    for (int o = 0; o < 32; ++o) acc[o] = bs[o];
    for (int kh = 0; kh < 3; ++kh) {
        int y = h + kh - 1;
        if ((unsigned)y >= 256u) continue;
        for (int kw = 0; kw < 3; ++kw) {
            int xx = w + kw - 1;
            if ((unsigned)xx >= 256u) continue;
            for (int ci = 0; ci < 32; ++ci) {
                float v = in[((size_t)(b * 32 + ci) << 16) + (y << 8) + xx];
                int wb = ci * 9 + kh * 3 + kw;
                #pragma unroll
                for (int o = 0; o < 32; ++o) acc[o] += v * ws[o * 288 + wb];
            }
        }
    }
    for (int o = 0; o < 32; ++o)
        out[((size_t)(b * 32 + o) << 16) + hw] = siluf(acc[o]);
}

__global__ void k_conv3(const float* __restrict__ in, const float* __restrict__ wgt,
                        const float* __restrict__ bias, float* __restrict__ out) {
    __shared__ float ws[3 * 32 * 9];
    __shared__ float bs[3];
    for (int i = threadIdx.x; i < 3 * 32 * 9; i += blockDim.x) ws[i] = wgt[i];
    if (threadIdx.x < 3) bs[threadIdx.x] = bias[threadIdx.x];
    __syncthreads();
    int pix = blockIdx.x * blockDim.x + threadIdx.x;
    if (pix >= BHW_) return;
    int b = pix >> 16, hw = pix & 65535;
    int h = hw >> 8, w = hw & 255;
    float acc[3];
    #pragma unroll
    for (int o = 0; o < 3; ++o) acc[o] = bs[o];
    for (int kh = 0; kh < 3; ++kh) {
        int y = h + kh - 1;
        if ((unsigned)y >= 256u) continue;
        for (int kw = 0; kw < 3; ++kw) {
            int xx = w + kw - 1;
            if ((unsigned)xx >= 256u) continue;
            for (int ci = 0; ci < 32; ++ci) {
                float v = in[((size_t)(b * 32 + ci) << 16) + (y << 8) + xx];
                int wb = ci * 9 + kh * 3 + kw;
                #pragma unroll
                for (int o = 0; o < 3; ++o) acc[o] += v * ws[o * 288 + wb];
            }
        }
    }
    for (int o = 0; o < 3; ++o)
        out[((size_t)(b * 3 + o) << 16) + hw] = acc[o];
}

// ---------- a = gelu(guide @ W_aop + b_aop), NHWC ----------
__global__ void k_aproj(const float* __restrict__ x, const float* __restrict__ W,
                        const float* __restrict__ bias, float* __restrict__ a) {
    int idx = blockIdx.x * blockDim.x + threadIdx.x;
    if (idx >= NPC) return;
    int pix = idx >> 6, c = idx & 63;
    int b = pix >> 16, hw = pix & 65535;
    float g0 = x[((size_t)(b * 9 + 7) << 16) + hw];
    float g1 = x[((size_t)(b * 9 + 8) << 16) + hw];
    float g2 = x[((size_t)(b * 9 + 5) << 16) + hw];
    float g3 = x[((size_t)(b * 9 + 6) << 16) + hw];
    float v = bias[c] + g0 * W[c] + g1 * W[64 + c] + g2 * W[128 + c] + g3 * W[192 + c];
    a[idx] = geluf(v);
}

// depthwise 3x3 + gelu, NHWC
__global__ void k_dw(const float* __restrict__ a, const float* __restrict__ dw,
                     float* __restrict__ a2) {
    int idx = blockIdx.x * blockDim.x + threadIdx.x;
    if (idx >= NPC) return;
    int pix = idx >> 6, c = idx & 63;
    int b = pix >> 16, hw = pix & 65535;
    int h = hw >> 8, w = hw & 255;
    float s = 0.f;
    for (int kh = 0; kh < 3; ++kh) {
        int y = h + kh - 1;
        if ((unsigned)y >= 256u) continue;
        for (int kw = 0; kw < 3; ++kw) {
            int xx = w + kw - 1;
            if ((unsigned)xx >= 256u) continue;
            s += a[(((size_t)(b << 16) + (y << 8) + xx) << 6) + c] * dw[(kh * 3 + kw) * 64 + c];
        }
    }
    a2[idx] = geluf(s);
}

// xg = core @ W_in + b_in, NHWC
__global__ void k_xproj(const float* __restrict__ x, const float* __restrict__ gray,
                        const float* __restrict__ recon, const float* __restrict__ W,
                        const float* __restrict__ bias, float* __restrict__ xg) {
    int idx = blockIdx.x * blockDim.x + threadIdx.x;
    if (idx >= NPC) return;
    int pix = idx >> 6, c = idx & 63;
    int b = pix >> 16, hw = pix & 65535;
    float c0 = x[((size_t)(b * 9 + 0) << 16) + hw];
    float c1 = x[((size_t)(b * 9 + 1) << 16) + hw];
    float c2 = x[((size_t)(b * 9 + 2) << 16) + hw];
    float c3 = gray[pix];
    float c4 = recon[((size_t)(b * 3 + 0) << 16) + hw];
    float c5 = recon[((size_t)(b * 3 + 1) << 16) + hw];
    float c6 = recon[((size_t)(b * 3 + 2) << 16) + hw];
    float v = bias[c] + c0 * W[c] + c1 * W[64 + c] + c2 * W[128 + c] + c3 * W[192 + c]
            + c4 * W[256 + c] + c5 * W[320 + c] + c6 * W[384 + c];
    xg[idx] = v;
}

// ---------- weight prep: padded combined [64 x 128] quad layout + out pairs ----------
__device__ __forceinline__ float wcomb(const float* Woff, const float* Wmask, int c, int j) {
    return j < 72 ? Woff[c * 72 + j] : (j < 108 ? Wmask[c * 36 + (j - 72)] : 0.f);
}

__global__ void k_prep(const float* __restrict__ Woff, const float* __restrict__ boff,
                       const float* __restrict__ Wmask, const float* __restrict__ bmask,
                       const float* __restrict__ Wout,
                       float* __restrict__ Wquad, float* __restrict__ Woutp,
                       float* __restrict__ bcomb) {
    int tid = threadIdx.x;
    int lane = tid & 63, i0 = tid >> 6;
    for (int i = i0; i < 32; i += 4) {
        int c0 = 2 * i, c1 = 2 * i + 1;
        float4 q;
        q.x = wcomb(Woff, Wmask, c0, lane);
        q.y = wcomb(Woff, Wmask, c0, lane + 64);
        q.z = wcomb(Woff, Wmask, c1, lane);
        q.w = wcomb(Woff, Wmask, c1, lane + 64);
        ((float4*)Wquad)[i * 64 + lane] = q;
        float2 p;
        p.x = Wout[c0 * 64 + lane];
        p.y = Wout[c1 * 64 + lane];
        ((float2*)Woutp)[i * 64 + lane] = p;
    }
    if (tid < 128) bcomb[tid] = tid < 72 ? boff[tid] : (tid < 108 ? bmask[tid - 72] : 0.f);
}

// ---------- DCNv3 core, restructured ----------
// block = 256 = 4 pixels x 64 lanes (wave == pixel)
__global__ __launch_bounds__(256) void k_dcn(
        const float* __restrict__ a2, const float* __restrict__ xg,
        const float* __restrict__ Wquad, const float* __restrict__ bcomb,
        const float* __restrict__ Woutp, const float* __restrict__ bout,
        float* __restrict__ out) {
    __shared__ __attribute__((aligned(16))) float a2s[4][64];
    __shared__ float offs[4][72];
    __shared__ float ms[4][36];
    __shared__ float invs[4][4];
    __shared__ __attribute__((aligned(16))) float taps[4][36][8];
    __shared__ __attribute__((aligned(16))) float accs[4][64];
    __shared__ float outs[4][65];

    int tid = threadIdx.x;
    int lp = tid >> 6;
    int lane = tid & 63;
    int pix = blockIdx.x * 4 + lp;
    int b = pix >> 16, hw = pix & 65535;
    int h = hw >> 8, w = hw & 255;

    a2s[lp][lane] = a2[((size_t)pix << 6) + lane];
    __syncthreads();

    // combined off(72)+mask(36)+pad(20) projection: lane owns cols {lane, lane+64}
    {
        float acc0 = bcomb[lane], acc1 = bcomb[64 + lane];
        const float2* av = (const float2*)&a2s[lp][0];
        const float4* Wq = (const float4*)Wquad;
        #pragma unroll 8
        for (int i = 0; i < 32; ++i) {
            float2 a = av[i];                // a2[2i], a2[2i+1] (uniform broadcast)
            float4 q = Wq[i * 64 + lane];
            acc0 += a.x * q.x; acc1 += a.x * q.y;
            acc0 += a.y * q.z; acc1 += a.y * q.w;
        }
        offs[lp][lane] = acc0;
        if (lane < 8) offs[lp][64 + lane] = acc1;
        else if (lane < 44) ms[lp][lane - 8] = __expf(acc1);   // softmax numerator (shift-free)
    }
    __syncthreads();

    if (lane < 4) {
        float s = 0.f;
        #pragma unroll
        for (int k = 0; k < 9; ++k) s += ms[lp][lane * 9 + k];
        invs[lp][lane] = 1.f / s;
    }
    __syncthreads();

    // tap precompute: lane j < 36 owns (g,k)
    if (lane < 36) {
        int j = lane;
        int g = j / 9, k = j - g * 9;
        float offy = offs[lp][2 * j], offx = offs[lp][2 * j + 1];
        float pm = ms[lp][j] * invs[lp][g];
        float ly = (float)(h + k / 3 - 1) + offy;
        float lx = (float)(w + k % 3 - 1) + offx;
        float y0f = floorf(ly), x0f = floorf(lx);
        float wy = ly - y0f, wx = lx - x0f;
        int iy0 = (int)y0f, ix0 = (int)x0f;
        int base = b << 16;
        #pragma unroll
        for (int dy = 0; dy < 2; ++dy) {
            #pragma unroll
            for (int dx = 0; dx < 2; ++dx) {
                int yi = iy0 + dy, xi = ix0 + dx;
                float wgt = (dy ? wy : 1.f - wy) * (dx ? wx : 1.f - wx) * pm;
                if (yi < 0 || yi > 255 || xi < 0 || xi > 255) wgt = 0.f;
                int yc = min(max(yi, 0), 255), xc = min(max(xi, 0), 255);
                int idx = base + (yc << 8) + xc;
                ((float2*)&taps[lp][j][0])[dy * 2 + dx] =
                    make_float2(__int_as_float(idx), wgt);
            }
        }
    }
    __syncthreads();

    // gather: channel == lane; 16 lanes share each (g,k) tap descriptor
    {
        int jrow = (lane >> 4) * 9;
        float acc = 0.f;
        #pragma unroll
        for (int k = 0; k < 9; ++k) {
            const float2* row = (const float2*)&taps[lp][jrow + k][0];
            #pragma unroll
            for (int t = 0; t < 4; ++t) {
                float2 pw = row[t];
                int idx = __float_as_int(pw.x);
                acc += pw.y * xg[(idx << 6) + lane];
            }
        }
        accs[lp][lane] = acc;
    }
    __syncthreads();

    // out projection with paired weights
    {
        float o = bout[lane];
        const float2* av = (const float2*)&accs[lp][0];
        const float2* Wp = (const float2*)Woutp;
        #pragma unroll 8
        for (int i = 0; i < 32; ++i) {
            float2 a = av[i];
            float2 p = Wp[i * 64 + lane];
            o += a.x * p.x + a.y * p.y;
        }
        outs[lp][lane] = o;
    }
    __syncthreads();

    int c = tid >> 2, wsub = tid & 3;
    int p0 = blockIdx.x * 4 + wsub;
    int b2 = p0 >> 16, rem = p0 & 65535;
    out[((size_t)b2 * 64 + c) * HW_ + rem] = outs[wsub][c];
}

extern "C" void kernel_launch(void* const* d_in, const int* in_sizes, int n_in,
                              void* d_out, int out_size, void* d_ws, size_t ws_size,
                              hipStream_t stream) {
    const float* x      = (const float*)d_in[0];
    const float* rw1    = (const float*)d_in[1];
    const float* rb1    = (const float*)d_in[2];
    const float* rw2    = (const float*)d_in[3];
    const float* rb2    = (const float*)d_in[4];
    const float* rw3    = (const float*)d_in[5];
    const float* rb3    = (const float*)d_in[6];
    const float* W_in   = (const float*)d_in[7];
    const float* b_in   = (const float*)d_in[8];
    const float* W_aop  = (const float*)d_in[9];
    const float* b_aop  = (const float*)d_in[10];
    const float* dw     = (const float*)d_in[11];
    const float* W_off  = (const float*)d_in[12];
    const float* b_off  = (const float*)d_in[13];
    const float* W_mask = (const float*)d_in[14];
    const float* b_mask = (const float*)d_in[15];
    const float* W_out  = (const float*)d_in[16];
    const float* b_out  = (const float*)d_in[17];
    float* out = (float*)d_out;

    float* ws = (float*)d_ws;
    float* Wquad = ws;                       // 8192
    float* Woutp = Wquad + 8192;             // 4096
    float* bcomb = Woutp + 4096;             // 128
    float* gray  = bcomb + 128;              // 131072
    float* h1    = gray + BHW_;              // 4194304
    float* h2    = h1 + (size_t)BHW_ * 32;   // 4194304
    float* recon = h2 + (size_t)BHW_ * 32;   // 393216
    float* a     = h1;                       // reuse h1+h2 after conv3
    float* a2    = recon + (size_t)BHW_ * 3; // 8388608
    float* xg    = a2 + (size_t)NPC;         // 8388608

    dim3 blk(256);
    dim3 gpix((BHW_ + 255) / 256);
    dim3 gpc((NPC + 255) / 256);

    k_prep<<<dim3(1), blk, 0, stream>>>(W_off, b_off, W_mask, b_mask, W_out,
                                        Wquad, Woutp, bcomb);
    k_poisson<<<dim3(32), dim3(512), 0, stream>>>(x, gray);
    k_conv1<<<gpix, blk, 0, stream>>>(x, rw1, rb1, h1);
    k_conv2<<<gpix, blk, 0, stream>>>(h1, rw2, rb2, h2);
    k_conv3<<<gpix, blk, 0, stream>>>(h2, rw3, rb3, recon);
    k_aproj<<<gpc, blk, 0, stream>>>(x, W_aop, b_aop, a);
    k_dw<<<gpc, blk, 0, stream>>>(a, dw, a2);
    k_xproj<<<gpc, blk, 0, stream>>>(x, gray, recon, W_in, b_in, xg);
    k_dcn<<<dim3(BHW_ / 4), blk, 0, stream>>>(a2, xg, Wquad, bcomb, Woutp, b_out, out);
}

// Round 3
// 379.444 us; speedup vs baseline: 1.6626x; 1.6626x over previous
//
#include <hip/hip_runtime.h>
#include <math.h>

#define H_ 256
#define W_ 256
#define HW_ 65536
#define BHW_ 131072   // B*H*W, B=2
#define NPC 8388608   // BHW_*64

__device__ __forceinline__ float geluf(float x) {
    const float k0 = 0.7978845608028654f; // sqrt(2/pi)
    return 0.5f * x * (1.f + tanhf(k0 * (x + 0.044715f * x * x * x)));
}
__device__ __forceinline__ float siluf(float x) {
    return x / (1.f + expf(-x));
}

// ---------- fused Poisson: div + 20 Jacobi iters ----------
// 128 blocks: 2 b x 8x8 tiles of 32x32, halo 20 (clipped at image edge).
// Tile-edge garbage propagates 1 cell/iter, ring r wrong after r+1 iters;
// interior at ring >= 20 exact after 20 iters.
__global__ __launch_bounds__(512) void k_poisson(const float* __restrict__ x,
                                                 float* __restrict__ gray) {
    __shared__ float u[72 * 73];
    __shared__ float dv[72 * 73];
    int bid = blockIdx.x;
    int b = bid >> 6, t = bid & 63;
    int qy = t >> 3, qx = t & 7;
    int y0i = qy << 5, x0i = qx << 5;
    int ys = max(y0i - 20, 0), ye = min(y0i + 51, 255);
    int xs = max(x0i - 20, 0), xe = min(x0i + 51, 255);
    int Ht = ye - ys + 1, Wt = xe - xs + 1;
    int ty = threadIdx.x >> 5, tx = threadIdx.x & 31;
    const float* x5 = x + ((size_t)(b * 9 + 5) << 16);
    const float* x6 = x + ((size_t)(b * 9 + 6) << 16);

    for (int yy = ty; yy < Ht; yy += 16)
        for (int xx = tx; xx < Wt; xx += 32) {
            int gy = ys + yy, gx = xs + xx;
            int i00 = (gy << 8) + gx;
            float v5 = x5[i00], v6 = x6[i00];
            float d = -0.5f * (v5 + v6) + 0.5f * (v5 - v6);
            if (gx > 0) d += 0.5f * (x5[i00 - 1] + x6[i00 - 1]);
            if (gy > 0) d -= 0.5f * (x5[i00 - 256] - x6[i00 - 256]);
            dv[yy * 73 + xx] = d;
            u[yy * 73 + xx] = 0.f;
        }
    __syncthreads();

    float nv[5][3];
    for (int it = 0; it < 20; ++it) {
        #pragma unroll
        for (int i = 0; i < 5; ++i) {
            int yy = ty + i * 16;
            #pragma unroll
            for (int j = 0; j < 3; ++j) {
                int xx = tx + j * 32;
                if (yy < Ht && xx < Wt) {
                    int ym = yy > 0 ? yy - 1 : 0, yp = yy < Ht - 1 ? yy + 1 : Ht - 1;
                    int xm = xx > 0 ? xx - 1 : 0, xp = xx < Wt - 1 ? xx + 1 : Wt - 1;
                    nv[i][j] = (u[ym * 73 + xx] + u[yp * 73 + xx] +
                                u[yy * 73 + xm] + u[yy * 73 + xp] - dv[yy * 73 + xx]) * 0.25f;
                }
            }
        }
        __syncthreads();
        #pragma unroll
        for (int i = 0; i < 5; ++i) {
            int yy = ty + i * 16;
            #pragma unroll
            for (int j = 0; j < 3; ++j) {
                int xx = tx + j * 32;
                if (yy < Ht && xx < Wt) u[yy * 73 + xx] = nv[i][j];
            }
        }
        __syncthreads();
    }

    for (int iy = ty; iy < 32; iy += 16) {
        int gy = y0i + iy, gx = x0i + tx;
        gray[((size_t)b << 16) + (gy << 8) + gx] = u[(gy - ys) * 73 + (gx - xs)];
    }
}

// ---------- conv1: 7 -> 32, silu; 2 threads/pixel x 16 outputs ----------
__global__ void k_conv1(const float* __restrict__ x, const float* __restrict__ wgt,
                        const float* __restrict__ bias, float* __restrict__ out) {
    __shared__ float ws[32 * 63];
    __shared__ float bs[32];
    for (int i = threadIdx.x; i < 32 * 63; i += 256) ws[i] = wgt[i];
    if (threadIdx.x < 32) bs[threadIdx.x] = bias[threadIdx.x];
    __syncthreads();
    int pix = blockIdx.x * 128 + (threadIdx.x & 127);
    int o0 = (threadIdx.x >> 7) * 16;
    int b = pix >> 16, hw = pix & 65535;
    int h = hw >> 8, w = hw & 255;
    float acc[16];
    #pragma unroll
    for (int o = 0; o < 16; ++o) acc[o] = bs[o0 + o];
    for (int kh = 0; kh < 3; ++kh) {
        int y = h + kh - 1;
        if ((unsigned)y >= 256u) continue;
        for (int kw = 0; kw < 3; ++kw) {
            int xx = w + kw - 1;
            if ((unsigned)xx >= 256u) continue;
            for (int ci = 0; ci < 7; ++ci) {
                float v = x[((size_t)(b * 9 + ci) << 16) + (y << 8) + xx];
                int wb = ci * 9 + kh * 3 + kw;
                #pragma unroll
                for (int o = 0; o < 16; ++o) acc[o] += v * ws[(o0 + o) * 63 + wb];
            }
        }
    }
    for (int o = 0; o < 16; ++o)
        out[((size_t)(b * 32 + o0 + o) << 16) + hw] = siluf(acc[o]);
}

// ---------- conv2: 32 -> 32, silu; 2 threads/pixel x 16 outputs ----------
__global__ void k_conv2(const float* __restrict__ in, const float* __restrict__ wgt,
                        const float* __restrict__ bias, float* __restrict__ out) {
    __shared__ float ws[32 * 288];
    __shared__ float bs[32];
    for (int i = threadIdx.x; i < 32 * 288; i += 256) ws[i] = wgt[i];
    if (threadIdx.x < 32) bs[threadIdx.x] = bias[threadIdx.x];
    __syncthreads();
    int pix = blockIdx.x * 128 + (threadIdx.x & 127);
    int o0 = (threadIdx.x >> 7) * 16;
    int b = pix >> 16, hw = pix & 65535;
    int h = hw >> 8, w = hw & 255;
    float acc[16];
    #pragma unroll
    for (int o = 0; o < 16; ++o) acc[o] = bs[o0 + o];
    for (int kh = 0; kh < 3; ++kh) {
        int y = h + kh - 1;
        if ((unsigned)y >= 256u) continue;
        for (int kw = 0; kw < 3; ++kw) {
            int xx = w + kw - 1;
            if ((unsigned)xx >= 256u) continue;
            for (int ci = 0; ci < 32; ++ci) {
                float v = in[((size_t)(b * 32 + ci) << 16) + (y << 8) + xx];
                int wb = ci * 9 + kh * 3 + kw;
                #pragma unroll
                for (int o = 0; o < 16; ++o) acc[o] += v * ws[(o0 + o) * 288 + wb];
            }
        }
    }
    for (int o = 0; o < 16; ++o)
        out[((size_t)(b * 32 + o0 + o) << 16) + hw] = siluf(acc[o]);
}

// ---------- conv3: 32 -> 3 ----------
__global__ void k_conv3(const float* __restrict__ in, const float* __restrict__ wgt,
                        const float* __restrict__ bias, float* __restrict__ out) {
    __shared__ float ws[3 * 288];
    __shared__ float bs[3];
    for (int i = threadIdx.x; i < 3 * 288; i += 256) ws[i] = wgt[i];
    if (threadIdx.x < 3) bs[threadIdx.x] = bias[threadIdx.x];
    __syncthreads();
    int pix = blockIdx.x * blockDim.x + threadIdx.x;
    if (pix >= BHW_) return;
    int b = pix >> 16, hw = pix & 65535;
    int h = hw >> 8, w = hw & 255;
    float acc[3];
    #pragma unroll
    for (int o = 0; o < 3; ++o) acc[o] = bs[o];
    for (int kh = 0; kh < 3; ++kh) {
        int y = h + kh - 1;
        if ((unsigned)y >= 256u) continue;
        for (int kw = 0; kw < 3; ++kw) {
            int xx = w + kw - 1;
            if ((unsigned)xx >= 256u) continue;
            for (int ci = 0; ci < 32; ++ci) {
                float v = in[((size_t)(b * 32 + ci) << 16) + (y << 8) + xx];
                int wb = ci * 9 + kh * 3 + kw;
                #pragma unroll
                for (int o = 0; o < 3; ++o) acc[o] += v * ws[o * 288 + wb];
            }
        }
    }
    for (int o = 0; o < 3; ++o)
        out[((size_t)(b * 3 + o) << 16) + hw] = acc[o];
}

// ---------- fused aproj + depthwise + gelu: tile 8x8, halo 1, all 64 ch in LDS ----------
__global__ __launch_bounds__(256) void k_adw(const float* __restrict__ x,
        const float* __restrict__ Wa, const float* __restrict__ ba,
        const float* __restrict__ dwW, float* __restrict__ a2) {
    __shared__ float at[100][64];
    int tid = threadIdx.x;
    int bid = blockIdx.x;
    int b = bid >> 10, tb = bid & 1023;
    int ty0 = (tb >> 5) << 3, tx0 = (tb & 31) << 3;
    const float* g0p = x + ((size_t)(b * 9 + 7) << 16);
    const float* g1p = x + ((size_t)(b * 9 + 8) << 16);
    const float* g2p = x + ((size_t)(b * 9 + 5) << 16);
    const float* g3p = x + ((size_t)(b * 9 + 6) << 16);
    int c = tid & 63;
    float w0 = Wa[c], w1 = Wa[64 + c], w2 = Wa[128 + c], w3 = Wa[192 + c];
    float bb = ba[c];
    #pragma unroll
    for (int rep = 0; rep < 25; ++rep) {
        int pos = rep * 4 + (tid >> 6);
        int py = pos / 10, pxx = pos - py * 10;
        int gy = ty0 - 1 + py, gx = tx0 - 1 + pxx;
        float v = 0.f;
        if ((unsigned)gy < 256u && (unsigned)gx < 256u) {
            int ii = (gy << 8) + gx;
            float tv = bb + g0p[ii] * w0 + g1p[ii] * w1 + g2p[ii] * w2 + g3p[ii] * w3;
            v = geluf(tv);
        }
        at[pos][c] = v;
    }
    __syncthreads();
    float dwr[9];
    #pragma unroll
    for (int k = 0; k < 9; ++k) dwr[k] = dwW[k * 64 + c];
    int pgrp = tid >> 6;
    #pragma unroll
    for (int i = 0; i < 16; ++i) {
        int pl = pgrp * 16 + i;
        int pyl = pl >> 3, pxl = pl & 7;
        float s = 0.f;
        #pragma unroll
        for (int kh = 0; kh < 3; ++kh)
            #pragma unroll
            for (int kw = 0; kw < 3; ++kw)
                s += at[(pyl + kh) * 10 + (pxl + kw)][c] * dwr[kh * 3 + kw];
        int gy = ty0 + pyl, gx = tx0 + pxl;
        a2[(((size_t)(b << 16) + (gy << 8) + gx) << 6) + c] = geluf(s);
    }
}

// ---------- xg = core @ W_in + b_in, NHWC ----------
__global__ void k_xproj(const float* __restrict__ x, const float* __restrict__ gray,
                        const float* __restrict__ recon, const float* __restrict__ W,
                        const float* __restrict__ bias, float* __restrict__ xg) {
    int idx = blockIdx.x * blockDim.x + threadIdx.x;
    if (idx >= NPC) return;
    int pix = idx >> 6, c = idx & 63;
    int b = pix >> 16, hw = pix & 65535;
    float c0 = x[((size_t)(b * 9 + 0) << 16) + hw];
    float c1 = x[((size_t)(b * 9 + 1) << 16) + hw];
    float c2 = x[((size_t)(b * 9 + 2) << 16) + hw];
    float c3 = gray[pix];
    float c4 = recon[((size_t)(b * 3 + 0) << 16) + hw];
    float c5 = recon[((size_t)(b * 3 + 1) << 16) + hw];
    float c6 = recon[((size_t)(b * 3 + 2) << 16) + hw];
    float v = bias[c] + c0 * W[c] + c1 * W[64 + c] + c2 * W[128 + c] + c3 * W[192 + c]
            + c4 * W[256 + c] + c5 * W[320 + c] + c6 * W[384 + c];
    xg[idx] = v;
}

// ---------- weight prep: combined [64 x 128] quad layout + out pairs ----------
__device__ __forceinline__ float wcomb(const float* Woff, const float* Wmask, int c, int j) {
    return j < 72 ? Woff[c * 72 + j] : (j < 108 ? Wmask[c * 36 + (j - 72)] : 0.f);
}

__global__ void k_prep(const float* __restrict__ Woff, const float* __restrict__ boff,
                       const float* __restrict__ Wmask, const float* __restrict__ bmask,
                       const float* __restrict__ Wout,
                       float* __restrict__ Wquad, float* __restrict__ Woutp,
                       float* __restrict__ bcomb) {
    int tid = threadIdx.x;
    int lane = tid & 63, i0 = tid >> 6;
    for (int i = i0; i < 32; i += 4) {
        int c0 = 2 * i, c1 = 2 * i + 1;
        float4 q;
        q.x = wcomb(Woff, Wmask, c0, lane);
        q.y = wcomb(Woff, Wmask, c0, lane + 64);
        q.z = wcomb(Woff, Wmask, c1, lane);
        q.w = wcomb(Woff, Wmask, c1, lane + 64);
        ((float4*)Wquad)[i * 64 + lane] = q;
        float2 p;
        p.x = Wout[c0 * 64 + lane];
        p.y = Wout[c1 * 64 + lane];
        ((float2*)Woutp)[i * 64 + lane] = p;
    }
    if (tid < 128) bcomb[tid] = tid < 72 ? boff[tid] : (tid < 108 ? bmask[tid - 72] : 0.f);
}

// ---------- DCNv3 core v3: 4 pixels per wave, 16 per block ----------
__global__ __launch_bounds__(256, 4) void k_dcn(
        const float* __restrict__ a2, const float* __restrict__ xg,
        const float* __restrict__ Wquad, const float* __restrict__ bcomb,
        const float* __restrict__ Woutp, const float* __restrict__ bout,
        float* __restrict__ out) {
    __shared__ __attribute__((aligned(16))) float bufA[16][64];   // a2 staging, then accs
    __shared__ __attribute__((aligned(16))) float offs[16][72];
    __shared__ float pms[16][36];
    __shared__ float invs[16][4];
    __shared__ __attribute__((aligned(16))) float taps[16][36][8]; // then outs[16][65]
    float (*outs)[65] = (float (*)[65])&taps[0][0][0];

    int tid = threadIdx.x;
    int wave = tid >> 6, lane = tid & 63;
    int pixbase = blockIdx.x << 4;
    int b = pixbase >> 16, hw0 = pixbase & 65535;
    int h = hw0 >> 8, w0 = hw0 & 255;
    int pw = wave << 2;

    // A: stage a2 for this wave's 4 pixels
    #pragma unroll
    for (int p = 0; p < 4; ++p)
        bufA[pw + p][lane] = a2[((size_t)(pixbase + pw + p) << 6) + lane];

    // B: combined off+mask projection (cols: lane, 64+lane), 4 px at once
    float acc0[4], acc1[4];
    {
        float b0 = bcomb[lane], b1 = bcomb[64 + lane];
        #pragma unroll
        for (int p = 0; p < 4; ++p) { acc0[p] = b0; acc1[p] = b1; }
        const float4* Wq = (const float4*)Wquad;
        #pragma unroll 4
        for (int i = 0; i < 32; ++i) {
            float4 q = Wq[i * 64 + lane];
            #pragma unroll
            for (int p = 0; p < 4; ++p) {
                float2 av = ((const float2*)&bufA[pw + p][0])[i];
                acc0[p] += av.x * q.x + av.y * q.z;
                acc1[p] += av.x * q.y + av.y * q.w;
            }
        }
    }
    // C: scatter to LDS; exp for mask logits (shift-free softmax)
    #pragma unroll
    for (int p = 0; p < 4; ++p) offs[pw + p][lane] = acc0[p];
    if (lane < 8) {
        #pragma unroll
        for (int p = 0; p < 4; ++p) offs[pw + p][64 + lane] = acc1[p];
    } else if (lane < 44) {
        #pragma unroll
        for (int p = 0; p < 4; ++p) pms[pw + p][lane - 8] = __expf(acc1[p]);
    }
    // D: per (px,g) reciprocal sums (wave-local)
    if (lane < 16) {
        int p = lane >> 2, g = lane & 3;
        const float* m = &pms[pw + p][g * 9];
        float s = m[0]+m[1]+m[2]+m[3]+m[4]+m[5]+m[6]+m[7]+m[8];
        invs[pw + p][g] = 1.f / s;
    }
    // E: tap descriptors, 144 jobs over 64 lanes
    #pragma unroll
    for (int rep = 0; rep < 3; ++rep) {
        int idx = rep * 64 + lane;
        if (idx < 144) {
            int p = idx / 36, j = idx - p * 36;
            int px = pw + p;
            int g = j / 9, k = j - g * 9;
            float2 oxy = ((const float2*)&offs[px][0])[j];
            float pm = pms[px][j] * invs[px][g];
            float ly = (float)(h + k / 3 - 1) + oxy.x;
            float lx = (float)(w0 + px + (k % 3) - 1) + oxy.y;
            float y0f = floorf(ly), x0f = floorf(lx);
            float wy = ly - y0f, wx = lx - x0f;
            int iy0 = (int)y0f, ix0 = (int)x0f;
            int base = b << 16;
            float4 t01, t23;
            {
                int yi = iy0, xi = ix0;
                float wgt = (1.f - wy) * (1.f - wx) * pm;
                if (yi < 0 || yi > 255 || xi < 0 || xi > 255) wgt = 0.f;
                int yc = min(max(yi, 0), 255), xc = min(max(xi, 0), 255);
                t01.x = __int_as_float(base + (yc << 8) + xc); t01.y = wgt;
            }
            {
                int yi = iy0, xi = ix0 + 1;
                float wgt = (1.f - wy) * wx * pm;
                if (yi < 0 || yi > 255 || xi < 0 || xi > 255) wgt = 0.f;
                int yc = min(max(yi, 0), 255), xc = min(max(xi, 0), 255);
                t01.z = __int_as_float(base + (yc << 8) + xc); t01.w = wgt;
            }
            {
                int yi = iy0 + 1, xi = ix0;
                float wgt = wy * (1.f - wx) * pm;
                if (yi < 0 || yi > 255 || xi < 0 || xi > 255) wgt = 0.f;
                int yc = min(max(yi, 0), 255), xc = min(max(xi, 0), 255);
                t23.x = __int_as_float(base + (yc << 8) + xc); t23.y = wgt;
            }
            {
                int yi = iy0 + 1, xi = ix0 + 1;
                float wgt = wy * wx * pm;
                if (yi < 0 || yi > 255 || xi < 0 || xi > 255) wgt = 0.f;
                int yc = min(max(yi, 0), 255), xc = min(max(xi, 0), 255);
                t23.z = __int_as_float(base + (yc << 8) + xc); t23.w = wgt;
            }
            ((float4*)&taps[px][j][0])[0] = t01;
            ((float4*)&taps[px][j][0])[1] = t23;
        }
    }
    // F: gather; lane = channel (g4*16+cg), 4 px per wave
    int g4 = lane >> 4;
    float gacc[4];
    #pragma unroll
    for (int p = 0; p < 4; ++p) {
        float acc = 0.f;
        const float4* tp = (const float4*)&taps[pw + p][g4 * 9][0];
        #pragma unroll
        for (int k = 0; k < 9; ++k) {
            float4 d0 = tp[2 * k], d1 = tp[2 * k + 1];
            acc += d0.y * xg[((size_t)__float_as_int(d0.x) << 6) + lane];
            acc += d0.w * xg[((size_t)__float_as_int(d0.z) << 6) + lane];
            acc += d1.y * xg[((size_t)__float_as_int(d1.x) << 6) + lane];
            acc += d1.w * xg[((size_t)__float_as_int(d1.z) << 6) + lane];
        }
        gacc[p] = acc;
    }
    // G: stage accs (bufA's a2 values are dead)
    #pragma unroll
    for (int p = 0; p < 4; ++p) bufA[pw + p][lane] = gacc[p];

    __syncthreads();   // all waves done with taps/offs/pms before outs overlay

    // H: out projection
    {
        float o[4];
        float bo = bout[lane];
        #pragma unroll
        for (int p = 0; p < 4; ++p) o[p] = bo;
        const float2* Wp = (const float2*)Woutp;
        #pragma unroll 4
        for (int i = 0; i < 32; ++i) {
            float2 pq = Wp[i * 64 + lane];
            #pragma unroll
            for (int p = 0; p < 4; ++p) {
                float2 av = ((const float2*)&bufA[pw + p][0])[i];
                o[p] += av.x * pq.x + av.y * pq.y;
            }
        }
        #pragma unroll
        for (int p = 0; p < 4; ++p) outs[pw + p][lane] = o[p];
    }
    __syncthreads();

    // transposed NCHW write: 16 consecutive w per channel row
    int cq = tid >> 4, px = tid & 15;
    size_t rowb = ((size_t)(b * 64) << 16) + hw0 + px;
    #pragma unroll
    for (int rep = 0; rep < 4; ++rep) {
        int c = cq + rep * 16;
        out[rowb + ((size_t)c << 16)] = outs[px][c];
    }
}

extern "C" void kernel_launch(void* const* d_in, const int* in_sizes, int n_in,
                              void* d_out, int out_size, void* d_ws, size_t ws_size,
                              hipStream_t stream) {
    const float* x      = (const float*)d_in[0];
    const float* rw1    = (const float*)d_in[1];
    const float* rb1    = (const float*)d_in[2];
    const float* rw2    = (const float*)d_in[3];
    const float* rb2    = (const float*)d_in[4];
    const float* rw3    = (const float*)d_in[5];
    const float* rb3    = (const float*)d_in[6];
    const float* W_in   = (const float*)d_in[7];
    const float* b_in   = (const float*)d_in[8];
    const float* W_aop  = (const float*)d_in[9];
    const float* b_aop  = (const float*)d_in[10];
    const float* dw     = (const float*)d_in[11];
    const float* W_off  = (const float*)d_in[12];
    const float* b_off  = (const float*)d_in[13];
    const float* W_mask = (const float*)d_in[14];
    const float* b_mask = (const float*)d_in[15];
    const float* W_out  = (const float*)d_in[16];
    const float* b_out  = (const float*)d_in[17];
    float* out = (float*)d_out;

    float* ws = (float*)d_ws;
    float* Wquad = ws;                        // 8192
    float* Woutp = Wquad + 8192;              // 4096
    float* bcomb = Woutp + 4096;              // 128
    float* gray  = bcomb + 128;               // 131072
    float* h1    = gray + BHW_;               // 4194304
    float* h2    = h1 + (size_t)BHW_ * 32;    // 4194304
    float* recon = h2 + (size_t)BHW_ * 32;    // 393216
    float* a2    = recon + (size_t)BHW_ * 3;  // 8388608
    float* xg    = a2 + (size_t)NPC;          // 8388608

    dim3 blk(256);
    dim3 gpc((NPC + 255) / 256);

    k_prep<<<dim3(1), blk, 0, stream>>>(W_off, b_off, W_mask, b_mask, W_out,
                                        Wquad, Woutp, bcomb);
    k_poisson<<<dim3(128), dim3(512), 0, stream>>>(x, gray);
    k_conv1<<<dim3(BHW_ / 128), blk, 0, stream>>>(x, rw1, rb1, h1);
    k_conv2<<<dim3(BHW_ / 128), blk, 0, stream>>>(h1, rw2, rb2, h2);
    k_conv3<<<dim3(BHW_ / 256), blk, 0, stream>>>(h2, rw3, rb3, recon);
    k_adw<<<dim3(BHW_ / 64), blk, 0, stream>>>(x, W_aop, b_aop, dw, a2);
    k_xproj<<<gpc, blk, 0, stream>>>(x, gray, recon, W_in, b_in, xg);
    k_dcn<<<dim3(BHW_ / 16), blk, 0, stream>>>(a2, xg, Wquad, bcomb, Woutp, b_out, out);
}